// Round 1
// baseline (4811.958 us; speedup 1.0000x reference)
//
#include <hip/hip_runtime.h>
#include <math.h>

// Problem constants (fixed by the reference): B=8, C=256, CQ=32, N=H*W=4096
constexpr int B_ = 8;
constexpr int C_ = 256;
constexpr int CQ_ = 32;
constexpr int N_ = 4096;

// ---------------------------------------------------------------------------
// Kernel 1: q/k projection.  q[b,o,n] = sum_c feat[b,c,n]*w1[o,c] + b1[o]
// One block per (b, 256-wide n tile). Weights transposed into LDS [c][o].
// ---------------------------------------------------------------------------
__global__ __launch_bounds__(256) void proj_qk(
    const float* __restrict__ feat,
    const float* __restrict__ w1, const float* __restrict__ b1,
    const float* __restrict__ w2, const float* __restrict__ b2,
    float* __restrict__ q, float* __restrict__ k)
{
    __shared__ float w1s[C_][CQ_ + 4];   // stride 36 floats: 16B-aligned rows
    __shared__ float w2s[C_][CQ_ + 4];

    const int b  = blockIdx.x;
    const int n0 = blockIdx.y * 256;
    const int t  = threadIdx.x;

    // stage weights transposed: src flat idx i = o*C + c
    for (int i = t; i < C_ * CQ_; i += 256) {
        int o = i >> 8;          // / C_
        int c = i & (C_ - 1);    // % C_
        w1s[c][o] = w1[i];
        w2s[c][o] = w2[i];
    }
    __syncthreads();

    float aq[CQ_], ak[CQ_];
#pragma unroll
    for (int o = 0; o < CQ_; ++o) { aq[o] = 0.f; ak[o] = 0.f; }

    const int n = n0 + t;
    for (int c = 0; c < C_; ++c) {
        float f = feat[((size_t)b * C_ + c) * N_ + n];
#pragma unroll
        for (int o = 0; o < CQ_; o += 4) {
            float4 wq = *reinterpret_cast<const float4*>(&w1s[c][o]);
            float4 wk = *reinterpret_cast<const float4*>(&w2s[c][o]);
            aq[o+0] += f * wq.x; aq[o+1] += f * wq.y;
            aq[o+2] += f * wq.z; aq[o+3] += f * wq.w;
            ak[o+0] += f * wk.x; ak[o+1] += f * wk.y;
            ak[o+2] += f * wk.z; ak[o+3] += f * wk.w;
        }
    }
#pragma unroll
    for (int o = 0; o < CQ_; ++o) {
        q[((size_t)b * CQ_ + o) * N_ + n] = aq[o] + b1[o];
        k[((size_t)b * CQ_ + o) * N_ + n] = ak[o] + b2[o];
    }
}

// ---------------------------------------------------------------------------
// Kernel 2: v projection.  v[b,co,n] = sum_c feat[b,c,n]*w3[co,c] + b3[co]
// Block: (b, 64-n tile, 128-cout tile); thread: lane=n, wave covers 32 couts.
// feat tile staged in LDS; w3 via wave-uniform (scalar) loads.
// ---------------------------------------------------------------------------
__global__ __launch_bounds__(256) void proj_v(
    const float* __restrict__ feat,
    const float* __restrict__ w3, const float* __restrict__ b3,
    float* __restrict__ v)
{
    __shared__ float fs[64][64];  // [ci][n] — writes n-consecutive, reads lane-consecutive

    const int b   = blockIdx.x;
    const int n0  = blockIdx.y * 64;
    const int co0 = blockIdx.z * 128;
    const int t    = threadIdx.x;
    const int lane = t & 63;
    const int wu   = __builtin_amdgcn_readfirstlane(t >> 6);  // wave id, force SGPR

    float acc[32];
#pragma unroll
    for (int j = 0; j < 32; ++j) acc[j] = 0.f;

    for (int ci0 = 0; ci0 < C_; ci0 += 64) {
        __syncthreads();
        for (int i = t; i < 64 * 64; i += 256) {
            int ci = i >> 6, n = i & 63;
            fs[ci][n] = feat[((size_t)b * C_ + ci0 + ci) * N_ + n0 + n];
        }
        __syncthreads();
        const float* wbase = &w3[(size_t)(co0 + wu * 32) * C_ + ci0];
        for (int jb = 0; jb < 32; jb += 8) {
#pragma unroll 4
            for (int ci = 0; ci < 64; ++ci) {
                float f = fs[ci][lane];
#pragma unroll
                for (int j = 0; j < 8; ++j)
                    acc[jb + j] += f * wbase[(size_t)(jb + j) * C_ + ci];
            }
        }
    }
#pragma unroll
    for (int j = 0; j < 32; ++j) {
        int co = co0 + wu * 32 + j;
        v[((size_t)b * C_ + co) * N_ + n0 + lane] = acc[j] + b3[co];
    }
}

// ---------------------------------------------------------------------------
// Kernel 3: flash attention + fused epilogue.
// Block = (b, 64 m's). Online softmax over n tiles of 64.
//   Phase A: s[m=lane][n] from qreg (VGPR) x k (scalar loads)
//   Phase B: acc[c][m=lane] += p[n][m] * v[c][n]  (v via scalar float4 loads)
// Epilogue: out = gamma * acc / l + feat
// ---------------------------------------------------------------------------
__global__ __launch_bounds__(256) void attn(
    const float* __restrict__ q, const float* __restrict__ k,
    const float* __restrict__ v, const float* __restrict__ feat,
    const float* __restrict__ gamma, float* __restrict__ out)
{
    constexpr int TM = 64;   // m rows per block
    constexpr int TN = 64;   // n tile
    constexpr int CPT = 64;  // channels per thread (C_/4 waves)

    __shared__ float ps[TN][TM];   // p tile, [n][m]: lane-consecutive
    __shared__ float pmax[4][TM];
    __shared__ float psum[4][TM];
    __shared__ float mrow[TM];
    __shared__ float lrow[TM];

    const int b    = blockIdx.x;
    const int m0   = blockIdx.y * TM;
    const int t    = threadIdx.x;
    const int lane = t & 63;
    const int wu   = __builtin_amdgcn_readfirstlane(t >> 6);

    if (t < TM) { mrow[t] = -1e30f; lrow[t] = 0.f; }

    // q fragment for this thread's row m = m0 + lane
    float qreg[CQ_];
#pragma unroll
    for (int c = 0; c < CQ_; ++c)
        qreg[c] = q[((size_t)b * CQ_ + c) * N_ + m0 + lane];

    float acc[CPT];
#pragma unroll
    for (int j = 0; j < CPT; ++j) acc[j] = 0.f;

    for (int n0 = 0; n0 < N_; n0 += TN) {
        // ---- Phase A: scores for n = n0 + wu*16 + jj ----
        float sv[16];
#pragma unroll
        for (int jj = 0; jj < 16; ++jj) sv[jj] = 0.f;
        for (int c = 0; c < CQ_; ++c) {
            const float* kp = &k[((size_t)b * CQ_ + c) * N_ + n0 + wu * 16];
#pragma unroll
            for (int jj = 0; jj < 16; ++jj)
                sv[jj] += qreg[c] * kp[jj];   // kp uniform -> s_load_dwordxN
        }
        float tmax = sv[0];
#pragma unroll
        for (int jj = 1; jj < 16; ++jj) tmax = fmaxf(tmax, sv[jj]);
        pmax[wu][lane] = tmax;
        __syncthreads();

        float mold = mrow[lane];
        float tm = fmaxf(fmaxf(pmax[0][lane], pmax[1][lane]),
                         fmaxf(pmax[2][lane], pmax[3][lane]));
        float mnew  = fmaxf(mold, tm);
        float alpha = __expf(mold - mnew);
        float psumv = 0.f;
#pragma unroll
        for (int jj = 0; jj < 16; ++jj) {
            float p = __expf(sv[jj] - mnew);
            psumv += p;
            ps[wu * 16 + jj][lane] = p;
        }
        psum[wu][lane] = psumv;
        __syncthreads();

        if (wu == 0) {
            lrow[lane] = lrow[lane] * alpha +
                         psum[0][lane] + psum[1][lane] + psum[2][lane] + psum[3][lane];
            mrow[lane] = mnew;
        }

        // ---- Phase B: accumulate PV for channels co = wu*64 + c ----
#pragma unroll
        for (int j = 0; j < CPT; ++j) acc[j] *= alpha;

        for (int nn = 0; nn < TN; nn += 4) {
            float p0 = ps[nn + 0][lane];
            float p1 = ps[nn + 1][lane];
            float p2 = ps[nn + 2][lane];
            float p3 = ps[nn + 3][lane];
            const float* vp = &v[((size_t)b * C_ + wu * CPT) * N_ + n0 + nn];
#pragma unroll
            for (int c = 0; c < CPT; ++c) {
                const float4 vv = *reinterpret_cast<const float4*>(vp + (size_t)c * N_);
                acc[c] += p0 * vv.x + p1 * vv.y + p2 * vv.z + p3 * vv.w;
            }
        }
    }
    __syncthreads();

    const float rl = 1.f / lrow[lane];
    const float g  = gamma[0];
#pragma unroll
    for (int j = 0; j < CPT; ++j) {
        size_t idx = ((size_t)b * C_ + wu * CPT + j) * N_ + m0 + lane;
        out[idx] = g * acc[j] * rl + feat[idx];
    }
}

// ---------------------------------------------------------------------------
extern "C" void kernel_launch(void* const* d_in, const int* in_sizes, int n_in,
                              void* d_out, int out_size, void* d_ws, size_t ws_size,
                              hipStream_t stream)
{
    (void)in_sizes; (void)n_in; (void)out_size; (void)ws_size;
    const float* feat  = (const float*)d_in[0];
    const float* w1    = (const float*)d_in[1];
    const float* b1    = (const float*)d_in[2];
    const float* w2    = (const float*)d_in[3];
    const float* b2    = (const float*)d_in[4];
    const float* w3    = (const float*)d_in[5];
    const float* b3    = (const float*)d_in[6];
    const float* gamma = (const float*)d_in[7];
    float* out = (float*)d_out;

    // workspace carve: q (4MB) | k (4MB) | v (32MB)  => 40MB total
    float* q = (float*)d_ws;
    float* k = q + (size_t)B_ * CQ_ * N_;
    float* v = k + (size_t)B_ * CQ_ * N_;

    proj_qk<<<dim3(B_, N_ / 256), 256, 0, stream>>>(feat, w1, b1, w2, b2, q, k);
    proj_v <<<dim3(B_, N_ / 64, C_ / 128), 256, 0, stream>>>(feat, w3, b3, v);
    attn   <<<dim3(B_, N_ / 64), 256, 0, stream>>>(q, k, v, feat, gamma, out);
}

// Round 2
// 448.432 us; speedup vs baseline: 10.7306x; 10.7306x over previous
//
#include <hip/hip_runtime.h>
#include <math.h>

// Problem constants (fixed by the reference): B=8, C=256, CQ=32, N=H*W=4096
constexpr int B_ = 8;
constexpr int C_ = 256;
constexpr int CQ_ = 32;
constexpr int N_ = 4096;

typedef __attribute__((ext_vector_type(8))) short short8;   // 8 bf16 (4 VGPRs)
typedef __attribute__((ext_vector_type(4))) float f32x4;    // MFMA C/D

__device__ __forceinline__ unsigned short bf16_1(float a) {
    unsigned ua = __float_as_uint(a);
    ua = (ua + 0x7FFFu + ((ua >> 16) & 1u)) >> 16;
    return (unsigned short)ua;
}
__device__ __forceinline__ unsigned bf16_2(float a, float b) {
    return (unsigned)bf16_1(a) | ((unsigned)bf16_1(b) << 16);
}

// ---------------------------------------------------------------------------
// Kernel 1: q/k projection -> qT/kT [b][n][32] bf16 (fragment-ready layout)
// ---------------------------------------------------------------------------
__global__ __launch_bounds__(256) void proj_qk(
    const float* __restrict__ feat,
    const float* __restrict__ w1, const float* __restrict__ b1,
    const float* __restrict__ w2, const float* __restrict__ b2,
    unsigned short* __restrict__ qT, unsigned short* __restrict__ kT)
{
    __shared__ float w1s[C_][CQ_ + 4];
    __shared__ float w2s[C_][CQ_ + 4];

    const int b  = blockIdx.x;
    const int n0 = blockIdx.y * 256;
    const int t  = threadIdx.x;

    for (int i = t; i < C_ * CQ_; i += 256) {
        int o = i >> 8;
        int c = i & (C_ - 1);
        w1s[c][o] = w1[i];
        w2s[c][o] = w2[i];
    }
    __syncthreads();

    float aq[CQ_], ak[CQ_];
#pragma unroll
    for (int o = 0; o < CQ_; ++o) { aq[o] = 0.f; ak[o] = 0.f; }

    const int n = n0 + t;
    for (int c = 0; c < C_; ++c) {
        float f = feat[((size_t)b * C_ + c) * N_ + n];
#pragma unroll
        for (int o = 0; o < CQ_; o += 4) {
            float4 wq = *reinterpret_cast<const float4*>(&w1s[c][o]);
            float4 wk = *reinterpret_cast<const float4*>(&w2s[c][o]);
            aq[o+0] += f * wq.x; aq[o+1] += f * wq.y;
            aq[o+2] += f * wq.z; aq[o+3] += f * wq.w;
            ak[o+0] += f * wk.x; ak[o+1] += f * wk.y;
            ak[o+2] += f * wk.z; ak[o+3] += f * wk.w;
        }
    }

    unsigned pq[16], pk[16];
#pragma unroll
    for (int o = 0; o < CQ_; o += 2) {
        pq[o >> 1] = bf16_2(aq[o] + b1[o], aq[o+1] + b1[o+1]);
        pk[o >> 1] = bf16_2(ak[o] + b2[o], ak[o+1] + b2[o+1]);
    }
    unsigned short* qrow = qT + ((size_t)b * N_ + n) * CQ_;
    unsigned short* krow = kT + ((size_t)b * N_ + n) * CQ_;
#pragma unroll
    for (int i = 0; i < 4; ++i) {
        uint4 uq, uk;
        uq.x = pq[4*i+0]; uq.y = pq[4*i+1]; uq.z = pq[4*i+2]; uq.w = pq[4*i+3];
        uk.x = pk[4*i+0]; uk.y = pk[4*i+1]; uk.z = pk[4*i+2]; uk.w = pk[4*i+3];
        *reinterpret_cast<uint4*>(qrow + 8*i) = uq;
        *reinterpret_cast<uint4*>(krow + 8*i) = uk;
    }
}

// ---------------------------------------------------------------------------
// Kernel 2: v projection -> v [b][c][n] bf16
// ---------------------------------------------------------------------------
__global__ __launch_bounds__(256) void proj_v(
    const float* __restrict__ feat,
    const float* __restrict__ w3, const float* __restrict__ b3,
    unsigned short* __restrict__ v)
{
    __shared__ float fs[64][64];

    const int b   = blockIdx.x;
    const int n0  = blockIdx.y * 64;
    const int co0 = blockIdx.z * 128;
    const int t    = threadIdx.x;
    const int lane = t & 63;
    const int wu   = __builtin_amdgcn_readfirstlane(t >> 6);

    float acc[32];
#pragma unroll
    for (int j = 0; j < 32; ++j) acc[j] = 0.f;

    for (int ci0 = 0; ci0 < C_; ci0 += 64) {
        __syncthreads();
        for (int i = t; i < 64 * 64; i += 256) {
            int ci = i >> 6, n = i & 63;
            fs[ci][n] = feat[((size_t)b * C_ + ci0 + ci) * N_ + n0 + n];
        }
        __syncthreads();
        const float* wbase = &w3[(size_t)(co0 + wu * 32) * C_ + ci0];
        for (int jb = 0; jb < 32; jb += 8) {
#pragma unroll 4
            for (int ci = 0; ci < 64; ++ci) {
                float f = fs[ci][lane];
#pragma unroll
                for (int j = 0; j < 8; ++j)
                    acc[jb + j] += f * wbase[(size_t)(jb + j) * C_ + ci];
            }
        }
    }
#pragma unroll
    for (int j = 0; j < 32; ++j) {
        int co = co0 + wu * 32 + j;
        v[((size_t)b * C_ + co) * N_ + n0 + lane] = bf16_1(acc[j] + b3[co]);
    }
}

// ---------------------------------------------------------------------------
// Kernel 3: MFMA flash attention, transposed orientation.
//   S^T[n][m] = mfma(K^T-frag, Q-frag)   (CQ=32 = one K-step)
//   online softmax: per-lane scalar state (col = m = lane&15)
//   O^T[c][m] += mfma(V^T-frag, P^T-frag)
// Epilogue: out[c][m] = gamma * O^T/l + feat, 16-consec-m coalesced stores.
// ---------------------------------------------------------------------------
__global__ __launch_bounds__(256) void attn(
    const unsigned short* __restrict__ qT, const unsigned short* __restrict__ kT,
    const unsigned short* __restrict__ v, const float* __restrict__ feat,
    const float* __restrict__ gamma, float* __restrict__ out)
{
    constexpr int TN = 32;      // n tile per iteration
    constexpr int PAD = 40;     // bf16 row stride (80 B) — bank-clean b128 reads

    __shared__ __align__(16) unsigned short ks[TN][PAD];      //  2.5 KB
    __shared__ __align__(16) unsigned short vs[C_][PAD];      // 20.0 KB
    __shared__ __align__(16) unsigned short ps[4][16][PAD];   //  5.0 KB

    const int b    = blockIdx.x;
    const int m0   = blockIdx.y * 64;
    const int t    = threadIdx.x;
    const int lane = t & 63;
    const int wu   = __builtin_amdgcn_readfirstlane(t >> 6);
    const int col  = lane & 15;        // m within wave tile
    const int grp  = lane >> 4;        // lane quad-group

    // Q fragment (B-operand): B[k=cq][col=m], 8 consecutive cq at fixed m
    const int m_glob = m0 + wu * 16 + col;
    short8 qf = *reinterpret_cast<const short8*>(
        &qT[((size_t)b * N_ + m_glob) * CQ_ + grp * 8]);

    f32x4 acc[16];
#pragma unroll
    for (int i = 0; i < 16; ++i) acc[i] = (f32x4){0.f, 0.f, 0.f, 0.f};

    float m_run = -1e30f;
    float l_run = 0.f;

    for (int n0 = 0; n0 < N_; n0 += TN) {
        __syncthreads();
        // stage K tile: kT[b][n0..n0+31][32] -> ks[n][cq]
        {
            int n = t >> 3, off = (t & 7) * 4;
            *reinterpret_cast<uint2*>(&ks[n][off]) =
                *reinterpret_cast<const uint2*>(&kT[((size_t)b * N_ + n0 + n) * CQ_ + off]);
        }
        // stage V tile: v[b][c][n0..n0+31] -> vs[c][n]
#pragma unroll
        for (int i = 0; i < 4; ++i) {
            int chunk = t + 256 * i;
            int c = chunk >> 2, off = (chunk & 3) * 8;
            *reinterpret_cast<uint4*>(&vs[c][off]) =
                *reinterpret_cast<const uint4*>(&v[((size_t)b * C_ + c) * N_ + n0 + off]);
        }
        __syncthreads();

        // ---- S^T = K^T · Q  (two 16-row n-subtiles) ----
        short8 a0 = *reinterpret_cast<const short8*>(&ks[col][grp * 8]);
        short8 a1 = *reinterpret_cast<const short8*>(&ks[16 + col][grp * 8]);
        f32x4 z = (f32x4){0.f, 0.f, 0.f, 0.f};
        f32x4 d0 = __builtin_amdgcn_mfma_f32_16x16x32_bf16(a0, qf, z, 0, 0, 0);
        f32x4 d1 = __builtin_amdgcn_mfma_f32_16x16x32_bf16(a1, qf, z, 0, 0, 0);

        // ---- online softmax (per-lane scalar state; rows n, col m fixed) ----
        float tmax = d0[0];
#pragma unroll
        for (int r = 1; r < 4; ++r) tmax = fmaxf(tmax, d0[r]);
#pragma unroll
        for (int r = 0; r < 4; ++r) tmax = fmaxf(tmax, d1[r]);
        tmax = fmaxf(tmax, __shfl_xor(tmax, 16));
        tmax = fmaxf(tmax, __shfl_xor(tmax, 32));

        float mnew  = fmaxf(m_run, tmax);
        float alpha = __expf(m_run - mnew);
        float p[8];
#pragma unroll
        for (int r = 0; r < 4; ++r) p[r]     = __expf(d0[r] - mnew);
#pragma unroll
        for (int r = 0; r < 4; ++r) p[4 + r] = __expf(d1[r] - mnew);
        float psum = 0.f;
#pragma unroll
        for (int r = 0; r < 8; ++r) psum += p[r];
        psum += __shfl_xor(psum, 16);
        psum += __shfl_xor(psum, 32);
        l_run = l_run * alpha + psum;
        m_run = mnew;

#pragma unroll
        for (int i = 0; i < 16; ++i) {
            acc[i][0] *= alpha; acc[i][1] *= alpha;
            acc[i][2] *= alpha; acc[i][3] *= alpha;
        }

        // ---- P^T -> per-wave LDS in [m][n] layout (b64 packed writes) ----
        uint2 w0, w1w;
        w0.x  = bf16_2(p[0], p[1]); w0.y  = bf16_2(p[2], p[3]);
        w1w.x = bf16_2(p[4], p[5]); w1w.y = bf16_2(p[6], p[7]);
        *reinterpret_cast<uint2*>(&ps[wu][col][grp * 4])      = w0;
        *reinterpret_cast<uint2*>(&ps[wu][col][16 + grp * 4]) = w1w;
        __asm__ volatile("s_waitcnt lgkmcnt(0)" ::: "memory");

        // ---- O^T += V^T · P^T ----
        short8 pf = *reinterpret_cast<const short8*>(&ps[wu][col][grp * 8]);
#pragma unroll
        for (int ct = 0; ct < 16; ++ct) {
            short8 vf = *reinterpret_cast<const short8*>(&vs[ct * 16 + col][grp * 8]);
            acc[ct] = __builtin_amdgcn_mfma_f32_16x16x32_bf16(vf, pf, acc[ct], 0, 0, 0);
        }
    }

    // ---- epilogue: out = gamma * O / l + feat ----
    const float rl = 1.f / l_run;
    const float g  = gamma[0];
#pragma unroll
    for (int ct = 0; ct < 16; ++ct) {
#pragma unroll
        for (int r = 0; r < 4; ++r) {
            int c = ct * 16 + grp * 4 + r;
            size_t idx = ((size_t)b * C_ + c) * N_ + m_glob;
            out[idx] = g * acc[ct][r] * rl + feat[idx];
        }
    }
}

// ---------------------------------------------------------------------------
extern "C" void kernel_launch(void* const* d_in, const int* in_sizes, int n_in,
                              void* d_out, int out_size, void* d_ws, size_t ws_size,
                              hipStream_t stream)
{
    (void)in_sizes; (void)n_in; (void)out_size; (void)ws_size;
    const float* feat  = (const float*)d_in[0];
    const float* w1    = (const float*)d_in[1];
    const float* b1    = (const float*)d_in[2];
    const float* w2    = (const float*)d_in[3];
    const float* b2    = (const float*)d_in[4];
    const float* w3    = (const float*)d_in[5];
    const float* b3    = (const float*)d_in[6];
    const float* gamma = (const float*)d_in[7];
    float* out = (float*)d_out;

    // ws carve (bf16): qT (2MB) | kT (2MB) | v (16MB) => 20MB
    unsigned short* qT = (unsigned short*)d_ws;
    unsigned short* kT = qT + (size_t)B_ * N_ * CQ_;
    unsigned short* v  = kT + (size_t)B_ * N_ * CQ_;

    proj_qk<<<dim3(B_, N_ / 256), 256, 0, stream>>>(feat, w1, b1, w2, b2, qT, kT);
    proj_v <<<dim3(B_, N_ / 64, C_ / 128), 256, 0, stream>>>(feat, w3, b3, v);
    attn   <<<dim3(B_, N_ / 64), 256, 0, stream>>>(qT, kT, v, feat, gamma, out);
}

// Round 4
// 240.434 us; speedup vs baseline: 20.0136x; 1.8651x over previous
//
#include <hip/hip_runtime.h>
#include <hip/hip_bf16.h>
#include <math.h>

// Problem constants: B=8, C=256, CQ=32, N=H*W=4096
constexpr int B_ = 8;
constexpr int C_ = 256;
constexpr int CQ_ = 32;
constexpr int N_ = 4096;
constexpr int NT = 64;            // n-tile
constexpr int TILES = N_ / NT;    // 64

typedef __attribute__((ext_vector_type(8))) short short8;   // 8 bf16
typedef __attribute__((ext_vector_type(4))) float f32x4;    // MFMA C/D

__device__ __forceinline__ unsigned short pk1(float a) {
    __hip_bfloat16 h = __float2bfloat16(a);
    return *reinterpret_cast<unsigned short*>(&h);
}
__device__ __forceinline__ unsigned pk2(float a, float b) {
    __hip_bfloat162 h = __float22bfloat162_rn(float2{a, b});
    return *reinterpret_cast<unsigned*>(&h);
}

// async global->LDS, 16B per lane (dest = wave-uniform base + lane*16)
__device__ __forceinline__ void async16(const unsigned short* g, unsigned short* l) {
    __builtin_amdgcn_global_load_lds(
        (const __attribute__((address_space(1))) unsigned int*)g,
        (__attribute__((address_space(3))) unsigned int*)l, 16, 0, 0);
}

// ---------------------------------------------------------------------------
// prep_w: w1/w2 -> wqk[mat][o][ci] bf16 pitch 264 ; w3 -> w3t[ks][c][ci&31] pitch 32
// ---------------------------------------------------------------------------
__global__ __launch_bounds__(256) void prep_w(
    const float* __restrict__ w1, const float* __restrict__ w2,
    const float* __restrict__ w3,
    unsigned short* __restrict__ wqk, unsigned short* __restrict__ w3t)
{
    int tid = blockIdx.x * 256 + threadIdx.x;
    int stride = gridDim.x * 256;
    for (int f = tid; f < 2 * 32 * 256; f += stride) {
        int mat = f >> 13, rest = f & 8191;
        int o = rest >> 8, ci = rest & 255;
        const float* w = mat ? w2 : w1;
        wqk[(mat * 32 + o) * 264 + ci] = pk1(w[o * 256 + ci]);
    }
    for (int f = tid; f < 256 * 256; f += stride) {
        int c = f >> 8, ci = f & 255;
        w3t[((ci >> 5) * 256 + c) * 32 + (ci & 31)] = pk1(w3[f]);
    }
}

// ---------------------------------------------------------------------------
// transpose_feat: feat [b][c][n] f32 -> featT [b][ks=ci/32][n][ci&31] bf16
// ---------------------------------------------------------------------------
__global__ __launch_bounds__(256) void transpose_feat(
    const float* __restrict__ feat, unsigned short* __restrict__ featT)
{
    __shared__ float sh[64][65];
    int b = blockIdx.x, n0 = blockIdx.y * 64, c0 = blockIdx.z * 64;
    int t = threadIdx.x;
    int nl = t & 63, cb = t >> 6;
#pragma unroll
    for (int i = 0; i < 16; ++i) {
        int cl = cb + i * 4;
        sh[cl][nl] = feat[((size_t)b * C_ + c0 + cl) * N_ + n0 + nl];
    }
    __syncthreads();
    int c2 = (t & 31) * 2, nb = t >> 5;
#pragma unroll
    for (int j = 0; j < 8; ++j) {
        int n = nb + j * 8;
        unsigned pv = pk2(sh[c2][n], sh[c2 + 1][n]);
        int cg = c0 + c2;
        int ks = cg >> 5, cij = cg & 31;
        *reinterpret_cast<unsigned*>(
            &featT[(((size_t)b * 8 + ks) * N_ + n0 + n) * 32 + cij]) = pv;
    }
}

// ---------------------------------------------------------------------------
// proj_qk (MFMA): qT[b][n][32], kws[b][tile][n&63][32] bf16
// block: 128 n rows x 32 o x K=256 ; wave: 32 n rows
// ---------------------------------------------------------------------------
__global__ __launch_bounds__(256) void proj_qk(
    const unsigned short* __restrict__ featT, const unsigned short* __restrict__ wqk,
    const float* __restrict__ b1, const float* __restrict__ b2,
    unsigned short* __restrict__ qT, unsigned short* __restrict__ kws)
{
    __shared__ __align__(16) unsigned short wsl[18432];  // 36864 B (33792 used)
    __shared__ __align__(16) unsigned short fa[128 * 32];

    int b = blockIdx.x, n0 = blockIdx.y * 128;
    int t = threadIdx.x, lane = t & 63;
    int wu = t >> 6, col = lane & 15, grp = lane >> 4;

    // stage both weight matrices once (9 instrs/wave; global has +3KB slack)
#pragma unroll
    for (int i = 0; i < 9; ++i)
        async16(wqk + wu * 4608 + i * 512 + lane * 8, wsl + wu * 4608 + i * 512);

    f32x4 acc[2][2][2];  // [msub][mat][ot]
#pragma unroll
    for (int ms = 0; ms < 2; ++ms)
#pragma unroll
        for (int ot = 0; ot < 2; ++ot) {
            float bq = b1[ot * 16 + col];
            float bk = b2[ot * 16 + col];
            acc[ms][0][ot] = (f32x4){bq, bq, bq, bq};
            acc[ms][1][ot] = (f32x4){bk, bk, bk, bk};
        }

    for (int ks = 0; ks < 8; ++ks) {
        __syncthreads();
        const unsigned short* src = featT + (((size_t)b * 8 + ks) * N_ + n0) * 32;
        // fa tile = 4096 shorts; wave covers 2 chunks x 512 => stride 1024 (R3 bug: was 2048)
#pragma unroll
        for (int i = 0; i < 2; ++i)
            async16(src + wu * 1024 + i * 512 + lane * 8, fa + wu * 1024 + i * 512);
        __syncthreads();

        short8 a[2], bf[2][2];
#pragma unroll
        for (int ms = 0; ms < 2; ++ms)
            a[ms] = *(const short8*)&fa[(wu * 32 + ms * 16 + col) * 32 + grp * 8];
#pragma unroll
        for (int mat = 0; mat < 2; ++mat)
#pragma unroll
            for (int ot = 0; ot < 2; ++ot)
                bf[mat][ot] = *(const short8*)
                    &wsl[(mat * 32 + ot * 16 + col) * 264 + ks * 32 + grp * 8];
#pragma unroll
        for (int ms = 0; ms < 2; ++ms)
#pragma unroll
            for (int mat = 0; mat < 2; ++mat)
#pragma unroll
                for (int ot = 0; ot < 2; ++ot)
                    acc[ms][mat][ot] = __builtin_amdgcn_mfma_f32_16x16x32_bf16(
                        a[ms], bf[mat][ot], acc[ms][mat][ot], 0, 0, 0);
    }

#pragma unroll
    for (int ms = 0; ms < 2; ++ms)
#pragma unroll
        for (int ot = 0; ot < 2; ++ot)
#pragma unroll
            for (int r = 0; r < 4; ++r) {
                int n = n0 + wu * 32 + ms * 16 + grp * 4 + r;
                int o = ot * 16 + col;
                qT[((size_t)b * N_ + n) * 32 + o] = pk1(acc[ms][0][ot][r]);
                kws[(((size_t)b * TILES + (n >> 6)) * 64 + (n & 63)) * 32 + o]
                    = pk1(acc[ms][1][ot][r]);
            }
}

// ---------------------------------------------------------------------------
// proj_v (MFMA): vws[b][tile][c][72] bf16 (cols 0..63 = n, 64..71 pad-junk)
// block: 256 c x 64 n x K=256 ; wave: 64 c
// ---------------------------------------------------------------------------
__global__ __launch_bounds__(256) void proj_v(
    const unsigned short* __restrict__ featT, const unsigned short* __restrict__ w3t,
    const float* __restrict__ b3, unsigned short* __restrict__ vws)
{
    __shared__ __align__(16) unsigned short w3s[256 * 32];
    __shared__ __align__(16) unsigned short fb[64 * 32];

    int b = blockIdx.x, tile = blockIdx.y;
    int n0 = tile * 64;
    int t = threadIdx.x, lane = t & 63;
    int wu = t >> 6, col = lane & 15, grp = lane >> 4;

    f32x4 acc[4][4];  // [ct][nsub]
#pragma unroll
    for (int ct = 0; ct < 4; ++ct) {
        int c = wu * 64 + ct * 16 + grp * 4;
        float4 bb = *(const float4*)&b3[c];
        f32x4 ini = (f32x4){bb.x, bb.y, bb.z, bb.w};
#pragma unroll
        for (int ns = 0; ns < 4; ++ns) acc[ct][ns] = ini;
    }

    for (int ks = 0; ks < 8; ++ks) {
        __syncthreads();
        const unsigned short* wsrc = w3t + ks * 256 * 32;
#pragma unroll
        for (int i = 0; i < 4; ++i)
            async16(wsrc + wu * 2048 + i * 512 + lane * 8, w3s + wu * 2048 + i * 512);
        const unsigned short* fsrc = featT + (((size_t)b * 8 + ks) * N_ + n0) * 32;
        async16(fsrc + wu * 512 + lane * 8, fb + wu * 512);
        __syncthreads();

        short8 a[4], bfr[4];
#pragma unroll
        for (int ct = 0; ct < 4; ++ct)
            a[ct] = *(const short8*)&w3s[(wu * 64 + ct * 16 + col) * 32 + grp * 8];
#pragma unroll
        for (int ns = 0; ns < 4; ++ns)
            bfr[ns] = *(const short8*)&fb[(ns * 16 + col) * 32 + grp * 8];
#pragma unroll
        for (int ct = 0; ct < 4; ++ct)
#pragma unroll
            for (int ns = 0; ns < 4; ++ns)
                acc[ct][ns] = __builtin_amdgcn_mfma_f32_16x16x32_bf16(
                    a[ct], bfr[ns], acc[ct][ns], 0, 0, 0);
    }

    unsigned short* vt = vws + ((size_t)b * TILES + tile) * 256 * 72;
#pragma unroll
    for (int ct = 0; ct < 4; ++ct)
#pragma unroll
        for (int ns = 0; ns < 4; ++ns)
#pragma unroll
            for (int r = 0; r < 4; ++r) {
                int c = wu * 64 + ct * 16 + grp * 4 + r;
                int n = ns * 16 + col;
                vt[c * 72 + n] = pk1(acc[ct][ns][r]);
            }
}

// ---------------------------------------------------------------------------
// attn: flash attention, no-max softmax (scores bounded ~|12|), MFMA both GEMMs.
// block = (b, 64 m). TN=64. wave: 64 channels x 64 m in PV (channel-split).
// Staging via global_load_lds from pre-swizzled images; K double-buffered,
// V prefetched across the barrier pair.
// ---------------------------------------------------------------------------
__global__ __launch_bounds__(256) void attn(
    const unsigned short* __restrict__ qT, const unsigned short* __restrict__ kws,
    const unsigned short* __restrict__ vws, const float* __restrict__ feat,
    const float* __restrict__ gamma, float* __restrict__ out)
{
    __shared__ __align__(16) unsigned short vs[256 * 72];     // 36864 B
    __shared__ __align__(16) unsigned short ks2[2][64 * 32];  //  8192 B
    __shared__ __align__(16) unsigned short ps[64 * 72];      //  9216 B
    __shared__ float lrow[64];

    int b = blockIdx.x, m0 = blockIdx.y * 64;
    int t = threadIdx.x, lane = t & 63;
    int wu = t >> 6, col = lane & 15, grp = lane >> 4;

    const int m_own = m0 + wu * 16 + col;   // this wave's S column
    short8 qf = *(const short8*)&qT[((size_t)b * N_ + m_own) * 32 + grp * 8];

    f32x4 acc[4][4];  // [ct][msub]
#pragma unroll
    for (int i = 0; i < 4; ++i)
#pragma unroll
        for (int j = 0; j < 4; ++j) acc[i][j] = (f32x4){0.f, 0.f, 0.f, 0.f};
    float l_run = 0.f;

    const unsigned short* kbase = kws + (size_t)b * TILES * 64 * 32;
    const unsigned short* vbase = vws + (size_t)b * TILES * 256 * 72;

    // prologue: stage K[0] (1 instr/wave) + V[0] (9 instrs/wave)
    async16(kbase + wu * 512 + lane * 8, ks2[0] + wu * 512);
#pragma unroll
    for (int i = 0; i < 9; ++i)
        async16(vbase + wu * 4608 + i * 512 + lane * 8, vs + wu * 4608 + i * 512);
    __syncthreads();

    for (int tt = 0; tt < TILES; ++tt) {
        const unsigned short* kcur = ks2[tt & 1];

        // ---- S^T = K^T · Q : 4 n-subtiles ----
        f32x4 d[4];
        f32x4 z = (f32x4){0.f, 0.f, 0.f, 0.f};
#pragma unroll
        for (int sub = 0; sub < 4; ++sub) {
            short8 a = *(const short8*)&kcur[(sub * 16 + col) * 32 + grp * 8];
            d[sub] = __builtin_amdgcn_mfma_f32_16x16x32_bf16(a, qf, z, 0, 0, 0);
        }

        // ---- softmax numerators (no max subtraction; |s| <~ 12) ----
        float ptot = 0.f;
#pragma unroll
        for (int sub = 0; sub < 4; ++sub) {
            float p0 = __expf(d[sub][0]);
            float p1 = __expf(d[sub][1]);
            float p2 = __expf(d[sub][2]);
            float p3 = __expf(d[sub][3]);
            ptot += (p0 + p1) + (p2 + p3);
            uint2 w;
            w.x = pk2(p0, p1);
            w.y = pk2(p2, p3);
            // P row m = wu*16+col, cols n = sub*16 + grp*4 .. +3
            *reinterpret_cast<uint2*>(&ps[(wu * 16 + col) * 72 + sub * 16 + grp * 4]) = w;
        }
        ptot += __shfl_xor(ptot, 16);
        ptot += __shfl_xor(ptot, 32);
        l_run += ptot;

        __syncthreads();   // X: P visible; V[tt] staged (drained)

        if (tt + 1 < TILES)   // prefetch K[tt+1], drains at Y (behind PV)
            async16(kbase + (tt + 1) * 2048 + wu * 512 + lane * 8,
                    ks2[(tt + 1) & 1] + wu * 512);

        // ---- O^T += V^T · P^T  (wave owns channels wu*64..wu*64+63) ----
        short8 pf[4][2];
#pragma unroll
        for (int ms = 0; ms < 4; ++ms)
#pragma unroll
            for (int h = 0; h < 2; ++h)
                pf[ms][h] = *(const short8*)&ps[(ms * 16 + col) * 72 + h * 32 + grp * 8];
#pragma unroll
        for (int ct = 0; ct < 4; ++ct) {
            int c = wu * 64 + ct * 16 + col;
            short8 vf0 = *(const short8*)&vs[c * 72 + grp * 8];
            short8 vf1 = *(const short8*)&vs[c * 72 + 32 + grp * 8];
#pragma unroll
            for (int ms = 0; ms < 4; ++ms)
                acc[ct][ms] = __builtin_amdgcn_mfma_f32_16x16x32_bf16(
                    vf0, pf[ms][0], acc[ct][ms], 0, 0, 0);
#pragma unroll
            for (int ms = 0; ms < 4; ++ms)
                acc[ct][ms] = __builtin_amdgcn_mfma_f32_16x16x32_bf16(
                    vf1, pf[ms][1], acc[ct][ms], 0, 0, 0);
        }

        __syncthreads();   // Y: K[tt+1] drained; PV reads done

        if (tt + 1 < TILES) {  // prefetch V[tt+1], drains at next X (behind S+exp)
            const unsigned short* vsrc = vbase + (size_t)(tt + 1) * 256 * 72;
#pragma unroll
            for (int i = 0; i < 9; ++i)
                async16(vsrc + wu * 4608 + i * 512 + lane * 8, vs + wu * 4608 + i * 512);
        }
    }

    // share per-column softmax denominators across waves
    if (grp == 0) lrow[wu * 16 + col] = l_run;
    __syncthreads();

    const float g = gamma[0];
#pragma unroll
    for (int ms = 0; ms < 4; ++ms) {
        float rl = 1.f / lrow[ms * 16 + col];
        int m = m0 + ms * 16 + col;
#pragma unroll
        for (int ct = 0; ct < 4; ++ct)
#pragma unroll
            for (int r = 0; r < 4; ++r) {
                int c = wu * 64 + ct * 16 + grp * 4 + r;
                size_t idx = ((size_t)b * C_ + c) * N_ + m;
                out[idx] = g * acc[ct][ms][r] * rl + feat[idx];
            }
    }
}

// ---------------------------------------------------------------------------
extern "C" void kernel_launch(void* const* d_in, const int* in_sizes, int n_in,
                              void* d_out, int out_size, void* d_ws, size_t ws_size,
                              hipStream_t stream)
{
    (void)in_sizes; (void)n_in; (void)out_size; (void)ws_size;
    const float* feat  = (const float*)d_in[0];
    const float* w1    = (const float*)d_in[1];
    const float* b1    = (const float*)d_in[2];
    const float* w2    = (const float*)d_in[3];
    const float* b2    = (const float*)d_in[4];
    const float* w3    = (const float*)d_in[5];
    const float* b3    = (const float*)d_in[6];
    const float* gamma = (const float*)d_in[7];
    float* out = (float*)d_out;

    // ws carve (bytes):
    // featT 16,777,216 | wqk 36,864 (33,792 + stage slack) | w3t 131,072
    // qT 2,097,152 | kws 2,097,152 | vws 18,874,368  => 40,013,824 total
    unsigned short* featT = (unsigned short*)d_ws;
    unsigned short* wqk   = featT + (size_t)B_ * 8 * N_ * 32;
    unsigned short* w3t   = wqk + 18432;            // 36,864 B region
    unsigned short* qT    = w3t + 8 * 256 * 32;
    unsigned short* kws   = qT + (size_t)B_ * N_ * 32;
    unsigned short* vws   = kws + (size_t)B_ * TILES * 64 * 32;

    prep_w        <<<32, 256, 0, stream>>>(w1, w2, w3, wqk, w3t);
    transpose_feat<<<dim3(B_, N_ / 64, C_ / 64), 256, 0, stream>>>(feat, featT);
    proj_qk       <<<dim3(B_, N_ / 128), 256, 0, stream>>>(featT, wqk, b1, b2, qT, kws);
    proj_v        <<<dim3(B_, TILES), 256, 0, stream>>>(featT, w3t, b3, vws);
    attn          <<<dim3(B_, N_ / 64), 256, 0, stream>>>(qT, kws, vws, feat, gamma, out);
}

// Round 5
// 213.007 us; speedup vs baseline: 22.5907x; 1.1288x over previous
//
#include <hip/hip_runtime.h>
#include <hip/hip_bf16.h>
#include <math.h>

// Problem constants: B=8, C=256, CQ=32, N=H*W=4096
constexpr int B_ = 8;
constexpr int C_ = 256;
constexpr int CQ_ = 32;
constexpr int N_ = 4096;
constexpr int NT = 64;            // n-tile
constexpr int TILES = N_ / NT;    // 64
constexpr int FP = 40;            // padded pitch (shorts) for 32-wide rows: bank-clean

typedef __attribute__((ext_vector_type(8))) short short8;   // 8 bf16
typedef __attribute__((ext_vector_type(4))) float f32x4;    // MFMA C/D

__device__ __forceinline__ unsigned short pk1(float a) {
    __hip_bfloat16 h = __float2bfloat16(a);
    return *reinterpret_cast<unsigned short*>(&h);
}
__device__ __forceinline__ unsigned pk2(float a, float b) {
    __hip_bfloat162 h = __float22bfloat162_rn(float2{a, b});
    return *reinterpret_cast<unsigned*>(&h);
}

// async global->LDS, 16B per lane (dest = wave-uniform base + lane*16)
__device__ __forceinline__ void async16(const unsigned short* g, unsigned short* l) {
    __builtin_amdgcn_global_load_lds(
        (const __attribute__((address_space(1))) unsigned int*)g,
        (__attribute__((address_space(3))) unsigned int*)l, 16, 0, 0);
}

// ---------------------------------------------------------------------------
// prep (merged): blocks 0..2047 transpose feat -> featT [b][ks][n][ci&31] pitch 40;
// blocks 2048..2079: w1/w2 -> wqk pitch 264 ; w3 -> w3t [ks][c][ci&31] pitch 40
// ---------------------------------------------------------------------------
__global__ __launch_bounds__(256) void prep(
    const float* __restrict__ feat,
    const float* __restrict__ w1, const float* __restrict__ w2,
    const float* __restrict__ w3,
    unsigned short* __restrict__ featT,
    unsigned short* __restrict__ wqk, unsigned short* __restrict__ w3t)
{
    __shared__ float sh[64][65];
    int id = blockIdx.x;
    int t = threadIdx.x;

    if (id < 2048) {
        int b = id >> 8, r = id & 255;
        int n0 = (r >> 2) * 64, c0 = (r & 3) * 64;
        int nl = t & 63, cb = t >> 6;
#pragma unroll
        for (int i = 0; i < 16; ++i) {
            int cl = cb + i * 4;
            sh[cl][nl] = feat[((size_t)b * C_ + c0 + cl) * N_ + n0 + nl];
        }
        __syncthreads();
        int c2 = (t & 31) * 2, nb = t >> 5;
#pragma unroll
        for (int j = 0; j < 8; ++j) {
            int n = nb + j * 8;
            unsigned pv = pk2(sh[c2][n], sh[c2 + 1][n]);
            int cg = c0 + c2;
            int ks = cg >> 5, cij = cg & 31;
            *reinterpret_cast<unsigned*>(
                &featT[(((size_t)b * 8 + ks) * N_ + n0 + n) * FP + cij]) = pv;
        }
    } else {
        int tid = (id - 2048) * 256 + t;
        const int stride = 32 * 256;
        for (int f = tid; f < 2 * 32 * 256; f += stride) {
            int mat = f >> 13, rest = f & 8191;
            int o = rest >> 8, ci = rest & 255;
            const float* w = mat ? w2 : w1;
            wqk[(mat * 32 + o) * 264 + ci] = pk1(w[o * 256 + ci]);
        }
        for (int f = tid; f < 256 * 256; f += stride) {
            int c = f >> 8, ci = f & 255;
            w3t[((size_t)(ci >> 5) * 256 + c) * FP + (ci & 31)] = pk1(w3[f]);
        }
    }
}

// ---------------------------------------------------------------------------
// proj (merged): blocks 0..255 = qk (b=id>>5, 128 n rows);
//                blocks 256..767 = v (b, 64-n tile).
// All LDS tiles pitch-40 (bank-clean) staged via global_load_lds.
// ---------------------------------------------------------------------------
__global__ __launch_bounds__(256) void proj(
    const unsigned short* __restrict__ featT, const unsigned short* __restrict__ wqk,
    const unsigned short* __restrict__ w3t,
    const float* __restrict__ b1, const float* __restrict__ b2,
    const float* __restrict__ b3,
    unsigned short* __restrict__ qT, unsigned short* __restrict__ kws,
    unsigned short* __restrict__ vws)
{
    __shared__ __align__(16) unsigned short smem[23552];   // 47,104 B
    int id = blockIdx.x;
    int t = threadIdx.x, lane = t & 63;
    int wu = t >> 6, col = lane & 15, grp = lane >> 4;

    if (id < 256) {
        // ---------------- qk branch ----------------
        unsigned short* wsl = smem;           // 18,432 shorts (pitch 264)
        unsigned short* fa  = smem + 18432;   //  5,120 shorts (128 rows x 40)
        int b = id >> 5, n0 = (id & 31) * 128;

#pragma unroll
        for (int i = 0; i < 9; ++i)
            async16(wqk + wu * 4608 + i * 512 + lane * 8, wsl + wu * 4608 + i * 512);

        f32x4 acc[2][2][2];  // [msub][mat][ot]
#pragma unroll
        for (int ms = 0; ms < 2; ++ms)
#pragma unroll
            for (int ot = 0; ot < 2; ++ot) {
                float bq = b1[ot * 16 + col];
                float bk = b2[ot * 16 + col];
                acc[ms][0][ot] = (f32x4){bq, bq, bq, bq};
                acc[ms][1][ot] = (f32x4){bk, bk, bk, bk};
            }

        for (int ks = 0; ks < 8; ++ks) {
            __syncthreads();
            const unsigned short* src = featT + (((size_t)b * 8 + ks) * N_ + n0) * FP;
            // 128*40 = 5120 shorts = 10 chunks of 512
#pragma unroll
            for (int i = 0; i < 3; ++i) {
                int ch = i * 4 + wu;
                if (ch < 10) async16(src + ch * 512 + lane * 8, fa + ch * 512);
            }
            __syncthreads();

            short8 a[2], bf[2][2];
#pragma unroll
            for (int ms = 0; ms < 2; ++ms)
                a[ms] = *(const short8*)&fa[(wu * 32 + ms * 16 + col) * FP + grp * 8];
#pragma unroll
            for (int mat = 0; mat < 2; ++mat)
#pragma unroll
                for (int ot = 0; ot < 2; ++ot)
                    bf[mat][ot] = *(const short8*)
                        &wsl[(mat * 32 + ot * 16 + col) * 264 + ks * 32 + grp * 8];
#pragma unroll
            for (int ms = 0; ms < 2; ++ms)
#pragma unroll
                for (int mat = 0; mat < 2; ++mat)
#pragma unroll
                    for (int ot = 0; ot < 2; ++ot)
                        acc[ms][mat][ot] = __builtin_amdgcn_mfma_f32_16x16x32_bf16(
                            a[ms], bf[mat][ot], acc[ms][mat][ot], 0, 0, 0);
        }

#pragma unroll
        for (int ms = 0; ms < 2; ++ms)
#pragma unroll
            for (int ot = 0; ot < 2; ++ot)
#pragma unroll
                for (int r = 0; r < 4; ++r) {
                    int n = n0 + wu * 32 + ms * 16 + grp * 4 + r;
                    int o = ot * 16 + col;
                    qT[((size_t)b * N_ + n) * 32 + o] = pk1(acc[ms][0][ot][r]);
                    kws[(((size_t)b * TILES + (n >> 6)) * 64 + (n & 63)) * FP + o]
                        = pk1(acc[ms][1][ot][r]);
                }
    } else {
        // ---------------- v branch ----------------
        unsigned short* w3s = smem;           // 10,240 shorts (256 rows x 40)
        unsigned short* fb  = smem + 10240;   //  2,560 shorts (64 rows x 40)
        int vid = id - 256;
        int b = vid >> 6, tile = vid & 63, n0 = tile * 64;

        f32x4 acc[4][4];  // [ct][nsub]
#pragma unroll
        for (int ct = 0; ct < 4; ++ct) {
            int c = wu * 64 + ct * 16 + grp * 4;
            float4 bb = *(const float4*)&b3[c];
            f32x4 ini = (f32x4){bb.x, bb.y, bb.z, bb.w};
#pragma unroll
            for (int ns = 0; ns < 4; ++ns) acc[ct][ns] = ini;
        }

        for (int ks = 0; ks < 8; ++ks) {
            __syncthreads();
            const unsigned short* wsrc = w3t + (size_t)ks * 256 * FP;
            // 256*40 = 10240 shorts = 20 chunks -> 5 per wave
#pragma unroll
            for (int i = 0; i < 5; ++i) {
                int ch = wu * 5 + i;
                async16(wsrc + ch * 512 + lane * 8, w3s + ch * 512);
            }
            const unsigned short* fsrc = featT + (((size_t)b * 8 + ks) * N_ + n0) * FP;
            // 64*40 = 2560 shorts = 5 chunks
#pragma unroll
            for (int i = 0; i < 2; ++i) {
                int ch = i * 4 + wu;
                if (ch < 5) async16(fsrc + ch * 512 + lane * 8, fb + ch * 512);
            }
            __syncthreads();

            short8 a[4], bfr[4];
#pragma unroll
            for (int ct = 0; ct < 4; ++ct)
                a[ct] = *(const short8*)&w3s[(wu * 64 + ct * 16 + col) * FP + grp * 8];
#pragma unroll
            for (int ns = 0; ns < 4; ++ns)
                bfr[ns] = *(const short8*)&fb[(ns * 16 + col) * FP + grp * 8];
#pragma unroll
            for (int ct = 0; ct < 4; ++ct)
#pragma unroll
                for (int ns = 0; ns < 4; ++ns)
                    acc[ct][ns] = __builtin_amdgcn_mfma_f32_16x16x32_bf16(
                        a[ct], bfr[ns], acc[ct][ns], 0, 0, 0);
        }

        unsigned short* vt = vws + ((size_t)b * TILES + tile) * 256 * 72;
#pragma unroll
        for (int ct = 0; ct < 4; ++ct)
#pragma unroll
            for (int ns = 0; ns < 4; ++ns)
#pragma unroll
                for (int r = 0; r < 4; ++r) {
                    int c = wu * 64 + ct * 16 + grp * 4 + r;
                    int n = ns * 16 + col;
                    vt[c * 72 + n] = pk1(acc[ct][ns][r]);
                }
    }
}

// ---------------------------------------------------------------------------
// attn: flash attention, no-max softmax, MFMA both GEMMs.
// block = (b, 64 m), 4 waves; wave owns 64 channels in PV.
// K tiles pitch-40 (bank-clean), double-buffered; V prefetched across barriers.
// ---------------------------------------------------------------------------
__global__ __launch_bounds__(256) void attn(
    const unsigned short* __restrict__ qT, const unsigned short* __restrict__ kws,
    const unsigned short* __restrict__ vws, const float* __restrict__ feat,
    const float* __restrict__ gamma, float* __restrict__ out)
{
    __shared__ __align__(16) unsigned short vs[256 * 72];     // 36,864 B
    __shared__ __align__(16) unsigned short ks2[2][64 * FP];  // 10,240 B
    __shared__ __align__(16) unsigned short ps[64 * 72];      //  9,216 B
    __shared__ float lrow[64];

    int b = blockIdx.x, m0 = blockIdx.y * 64;
    int t = threadIdx.x, lane = t & 63;
    int wu = t >> 6, col = lane & 15, grp = lane >> 4;

    const int m_own = m0 + wu * 16 + col;   // this wave's S column
    short8 qf = *(const short8*)&qT[((size_t)b * N_ + m_own) * 32 + grp * 8];

    f32x4 acc[4][4];  // [ct][msub]
#pragma unroll
    for (int i = 0; i < 4; ++i)
#pragma unroll
        for (int j = 0; j < 4; ++j) acc[i][j] = (f32x4){0.f, 0.f, 0.f, 0.f};
    float l_run = 0.f;

    const unsigned short* kbase = kws + (size_t)b * TILES * 64 * FP;
    const unsigned short* vbase = vws + (size_t)b * TILES * 256 * 72;

    // prologue: stage K[0] (64*40 = 5 chunks) + V[0] (36 chunks)
#pragma unroll
    for (int i = 0; i < 2; ++i) {
        int ch = i * 4 + wu;
        if (ch < 5) async16(kbase + ch * 512 + lane * 8, ks2[0] + ch * 512);
    }
#pragma unroll
    for (int i = 0; i < 9; ++i)
        async16(vbase + wu * 4608 + i * 512 + lane * 8, vs + wu * 4608 + i * 512);
    __syncthreads();

    for (int tt = 0; tt < TILES; ++tt) {
        const unsigned short* kcur = ks2[tt & 1];

        // ---- S^T = K^T · Q : 4 n-subtiles ----
        f32x4 d[4];
        f32x4 z = (f32x4){0.f, 0.f, 0.f, 0.f};
#pragma unroll
        for (int sub = 0; sub < 4; ++sub) {
            short8 a = *(const short8*)&kcur[(sub * 16 + col) * FP + grp * 8];
            d[sub] = __builtin_amdgcn_mfma_f32_16x16x32_bf16(a, qf, z, 0, 0, 0);
        }

        // ---- softmax numerators (no max subtraction; |s| <~ 12) ----
        float ptot = 0.f;
#pragma unroll
        for (int sub = 0; sub < 4; ++sub) {
            float p0 = __expf(d[sub][0]);
            float p1 = __expf(d[sub][1]);
            float p2 = __expf(d[sub][2]);
            float p3 = __expf(d[sub][3]);
            ptot += (p0 + p1) + (p2 + p3);
            uint2 w;
            w.x = pk2(p0, p1);
            w.y = pk2(p2, p3);
            *reinterpret_cast<uint2*>(&ps[(wu * 16 + col) * 72 + sub * 16 + grp * 4]) = w;
        }
        ptot += __shfl_xor(ptot, 16);
        ptot += __shfl_xor(ptot, 32);
        l_run += ptot;

        __syncthreads();   // X: P visible; V[tt] staged (drained)

        if (tt + 1 < TILES) {  // prefetch K[tt+1] into other buffer; drains at Y
            const unsigned short* src = kbase + (size_t)(tt + 1) * 64 * FP;
            unsigned short* dst = ks2[(tt + 1) & 1];
#pragma unroll
            for (int i = 0; i < 2; ++i) {
                int ch = i * 4 + wu;
                if (ch < 5) async16(src + ch * 512 + lane * 8, dst + ch * 512);
            }
        }

        // ---- O^T += V^T · P^T  (wave owns channels wu*64..wu*64+63) ----
        short8 pf[4][2];
#pragma unroll
        for (int ms = 0; ms < 4; ++ms)
#pragma unroll
            for (int h = 0; h < 2; ++h)
                pf[ms][h] = *(const short8*)&ps[(ms * 16 + col) * 72 + h * 32 + grp * 8];
#pragma unroll
        for (int ct = 0; ct < 4; ++ct) {
            int c = wu * 64 + ct * 16 + col;
            short8 vf0 = *(const short8*)&vs[c * 72 + grp * 8];
            short8 vf1 = *(const short8*)&vs[c * 72 + 32 + grp * 8];
#pragma unroll
            for (int ms = 0; ms < 4; ++ms)
                acc[ct][ms] = __builtin_amdgcn_mfma_f32_16x16x32_bf16(
                    vf0, pf[ms][0], acc[ct][ms], 0, 0, 0);
#pragma unroll
            for (int ms = 0; ms < 4; ++ms)
                acc[ct][ms] = __builtin_amdgcn_mfma_f32_16x16x32_bf16(
                    vf1, pf[ms][1], acc[ct][ms], 0, 0, 0);
        }

        __syncthreads();   // Y: K[tt+1] drained; PV reads done

        if (tt + 1 < TILES) {  // prefetch V[tt+1]; drains at next X
            const unsigned short* vsrc = vbase + (size_t)(tt + 1) * 256 * 72;
#pragma unroll
            for (int i = 0; i < 9; ++i)
                async16(vsrc + wu * 4608 + i * 512 + lane * 8, vs + wu * 4608 + i * 512);
        }
    }

    if (grp == 0) lrow[wu * 16 + col] = l_run;
    __syncthreads();

    const float g = gamma[0];
#pragma unroll
    for (int ms = 0; ms < 4; ++ms) {
        float rl = 1.f / lrow[ms * 16 + col];
        int m = m0 + ms * 16 + col;
#pragma unroll
        for (int ct = 0; ct < 4; ++ct)
#pragma unroll
            for (int r = 0; r < 4; ++r) {
                int c = wu * 64 + ct * 16 + grp * 4 + r;
                size_t idx = ((size_t)b * C_ + c) * N_ + m;
                out[idx] = g * acc[ct][ms][r] * rl + feat[idx];
            }
    }
}

// ---------------------------------------------------------------------------
extern "C" void kernel_launch(void* const* d_in, const int* in_sizes, int n_in,
                              void* d_out, int out_size, void* d_ws, size_t ws_size,
                              hipStream_t stream)
{
    (void)in_sizes; (void)n_in; (void)out_size; (void)ws_size;
    const float* feat  = (const float*)d_in[0];
    const float* w1    = (const float*)d_in[1];
    const float* b1    = (const float*)d_in[2];
    const float* w2    = (const float*)d_in[3];
    const float* b2    = (const float*)d_in[4];
    const float* w3    = (const float*)d_in[5];
    const float* b3    = (const float*)d_in[6];
    const float* gamma = (const float*)d_in[7];
    float* out = (float*)d_out;

    // ws carve (bytes):
    // featT 20,971,520 | wqk 36,864 (33,792 + DMA slack) | w3t 163,840
    // qT 2,097,152 | kws 2,621,440 | vws 18,874,368  => 44,765,184 total
    unsigned short* featT = (unsigned short*)d_ws;
    unsigned short* wqk   = featT + (size_t)B_ * 8 * N_ * FP;
    unsigned short* w3t   = wqk + 18432;
    unsigned short* qT    = w3t + (size_t)8 * 256 * FP;
    unsigned short* kws   = qT + (size_t)B_ * N_ * 32;
    unsigned short* vws   = kws + (size_t)B_ * TILES * 64 * FP;

    prep<<<2048 + 32, 256, 0, stream>>>(feat, w1, w2, w3, featT, wqk, w3t);
    proj<<<768, 256, 0, stream>>>(featT, wqk, w3t, b1, b2, b3, qT, kws, vws);
    attn<<<dim3(B_, N_ / 64), 256, 0, stream>>>(qT, kws, vws, feat, gamma, out);
}